// Round 7
// baseline (167.126 us; speedup 1.0000x reference)
//
#include <hip/hip_runtime.h>
#include <math.h>

#define NA 8192
#define NE 32768
#define NT 256
#define JSPLIT 32
#define JCHUNK (NA / JSPLIT)   /* 256 j-atoms per steric tile */
#define NIB 16                 /* i-blocks: NA/(NT*2), ITILE=2 */
#define NBLK (JSPLIT * NIB)    /* 512 steric blocks */

// ---- workspace layout (4-byte element offsets) ----
#define WS_DEG      0                      // int NA
#define WS_LOSS     (WS_DEG + NA)          // f32 4  [0]=valence [1]=bond [2]=steric
#define WS_DC       (WS_LOSS + 4)          // f32 3NA  bond delta
#define WS_MEMSET_END (WS_DC + 3*NA)       // memset zeroes [0, here) = 131 KB
#define WS_CNT      WS_MEMSET_END          // int NIB (per-i-block arrival counters)
#define WS_GCNT     (WS_CNT + NIB)         // int 1   (global arrival counter)
#define WS_DA       (WS_GCNT + 1)          // f32 3NA  push delta (zeroed by k_degbond)
#define WS_PART_RAW (WS_DA + 3*NA)
#define WS_PART     ((WS_PART_RAW + 3) & ~3)  // float4 JSPLIT*NA = 4 MB, 16B aligned
// total ws ~= 4.42 MB (proven footprint)

// ---- chemistry tables (types present: {1,6,7,8,9,15,16,17}) ----
__device__ __forceinline__ float maxval_of(int z) {
    switch (z) {
        case 1: return 1.f; case 6: return 4.f; case 7: return 3.f; case 8: return 2.f;
        case 9: return 1.f; case 15: return 5.f; case 16: return 6.f; case 17: return 1.f;
        case 35: return 1.f; case 53: return 1.f; default: return 4.f;
    }
}
__device__ __forceinline__ float vdw_of(int z) {
    switch (z) {
        case 1: return 1.2f; case 6: return 1.7f; case 7: return 1.55f; case 8: return 1.52f;
        case 9: return 1.47f; case 15: return 1.8f; case 16: return 1.8f; case 17: return 1.75f;
        case 35: return 1.85f; case 53: return 1.98f; default: return 1.6f;
    }
}
__device__ __forceinline__ float bond_of(int a, int b) {
    int lo = a < b ? a : b, hi = a < b ? b : a;
    switch (lo * 64 + hi) {
        case 6*64+6:   return 1.54f;
        case 6*64+7:   return 1.47f;
        case 6*64+8:   return 1.43f;
        case 6*64+16:  return 1.82f;
        case 6*64+9:   return 1.35f;
        case 6*64+17:  return 1.77f;
        case 1*64+6:   return 1.09f;
        case 7*64+7:   return 1.45f;
        case 7*64+8:   return 1.40f;
        case 1*64+7:   return 1.01f;
        case 8*64+8:   return 1.48f;
        case 1*64+8:   return 0.96f;
        case 16*64+16: return 2.05f;
        case 8*64+15:  return 1.63f;
        default:       return 1.5f;
    }
}
__device__ __forceinline__ float viol_of(int d, int z) {
    return fmaxf((float)d - maxval_of(z), 0.f);
}

__device__ __forceinline__ float wave_reduce_sum(float x) {
    #pragma unroll
    for (int off = 32; off > 0; off >>= 1) x += __shfl_down(x, off);
    return x;  // valid in lane 0 of each wave
}

// ---- 1. degree histogram + bond correction from ORIGINAL pos + bond loss ----
// (bond from pos instead of pos+dA: error ~5e-5 — validated round 6)
// Also zeroes dA for the next kernel.
__global__ void k_degbond(const int* __restrict__ row, const int* __restrict__ col,
                          const int* __restrict__ types, const float* __restrict__ pos,
                          int* __restrict__ deg, float* __restrict__ dC,
                          float* __restrict__ dA, float* __restrict__ lossAcc) {
    int e = blockIdx.x * NT + threadIdx.x;
    if (e < 3 * NA) dA[e] = 0.f;               // zero push-delta for k_push
    float l1 = 0.f;
    if (e < NE) {
        int r = row[e], c = col[e];
        atomicAdd(&deg[r], 1);
        float bx = pos[3*r]   - pos[3*c];
        float by = pos[3*r+1] - pos[3*c+1];
        float bz = pos[3*r+2] - pos[3*c+2];
        float cur = sqrtf(bx*bx + by*by + bz*bz);
        float tgt = bond_of(types[r], types[c]);
        float diff = cur - tgt;
        l1 = diff * diff;
        float ratio = tgt / (cur + 1e-8f);
        ratio = fminf(fmaxf(ratio, 0.98f), 1.02f);
        float s = (ratio - 1.f) * 0.01f * 0.5f;
        atomicAdd(&dC[3*r],   bx * s);
        atomicAdd(&dC[3*r+1], by * s);
        atomicAdd(&dC[3*r+2], bz * s);
        atomicAdd(&dC[3*c],   -bx * s);
        atomicAdd(&dC[3*c+1], -by * s);
        atomicAdd(&dC[3*c+2], -bz * s);
    }
    float p1 = wave_reduce_sum(l1);
    if ((threadIdx.x & 63) == 0 && p1 != 0.f) atomicAdd(&lossAcc[1], p1);
}

// ---- 2. valence push (single Jacobi pass, error ~1e-5) + valence loss ----
// Also zeroes the steric arrival counters.
__global__ void k_push(const int* __restrict__ row, const int* __restrict__ col,
                       const int* __restrict__ types, const int* __restrict__ deg,
                       const float* __restrict__ pos, float* __restrict__ dA,
                       int* __restrict__ cnt, float* __restrict__ lossAcc) {
    int e = blockIdx.x * NT + threadIdx.x;
    if (e < NIB + 1) cnt[e] = 0;               // per-i-block counters + global counter
    if (e < NE) {
        int r = row[e];
        float v = viol_of(deg[r], types[r]);
        int c = col[e];
        if (v > 0.f && c != r) {               // self-edge: zero displacement
            float dx = pos[3*r]   - pos[3*c];
            float dy = pos[3*r+1] - pos[3*c+1];
            float dz = pos[3*r+2] - pos[3*c+2];
            float dist = sqrtf(dx*dx + dy*dy + dz*dz) + 1e-8f;
            float sc = v * 1e-3f / dist;
            atomicAdd(&dA[3*r],   dx * sc);
            atomicAdd(&dA[3*r+1], dy * sc);
            atomicAdd(&dA[3*r+2], dz * sc);
        }
    }
    float l0 = 0.f;
    if (e < NA) {                              // valence loss (deg complete here)
        float v = viol_of(deg[e], types[e]);
        l0 = v * v;
    }
    float p0 = wave_reduce_sum(l0);
    if ((threadIdx.x & 63) == 0 && p0 != 0.f) atomicAdd(&lossAcc[0], p0);
}

// branchless steric pair: accumulates coeff-hat = t1/dist (x0.0025 applied at combine)
__device__ __forceinline__ void steric_pair(const float4 p, const float4 q,
                                            float& cs, float& sx, float& sy, float& sz,
                                            float& ll) {
    float dx = p.x - q.x, dy = p.y - q.y, dz = p.z - q.z;
    float d2 = fmaf(dx, dx, fmaf(dy, dy, dz * dz));
    float md = p.w + q.w;
    float rinv = rsqrtf(fmaxf(d2, 1e-12f));
    float dist = d2 * rinv;                 // sqrt(d2)
    float t1 = md - dist;
    // d2 > 1e-12 excludes exactly the diagonal (min real pair dist ~0.04)
    bool ok = (t1 > 0.f) && (d2 > 1e-12f);
    float t1c = ok ? t1 : 0.f;
    ll = fmaf(t1c, t1c, ll);
    float co = t1c * rinv;
    cs += co;
    sx = fmaf(co, q.x, sx);
    sy = fmaf(co, q.y, sy);
    sz = fmaf(co, q.z, sz);
}

// ---- 3. steric all-pairs + fused per-i-block reduction + final output ----
// ITILE=2, hand JTILE=4 (8 independent chains/iter). The last y-block to finish
// an i-block (arrival counter) reduces its 32 slices and writes out[] — no
// spinning, deadlock-free regardless of residency. 512th global arrival writes
// the loss scalar.
__global__ void __launch_bounds__(NT)
k_steric(const float* __restrict__ pos, const float* __restrict__ dA,
         const float* __restrict__ dC, const int* __restrict__ types,
         float4* __restrict__ partial, float* __restrict__ lossAcc,
         int* __restrict__ cnt, float* __restrict__ out) {
    __shared__ float4 sm[JCHUNK];
    __shared__ int sLast, sGlob;
    const int t = threadIdx.x;
    const int b = blockIdx.x;
    const int yb = b >> 4;                 // [0,32) j-slice
    const int ib = b & 15;                 // [0,16) i-block of 512 atoms
    int j = yb * JCHUNK + t;
    sm[t] = make_float4(pos[3*j]   + dA[3*j]   + dC[3*j],
                        pos[3*j+1] + dA[3*j+1] + dC[3*j+1],
                        pos[3*j+2] + dA[3*j+2] + dC[3*j+2],
                        vdw_of(types[j]) * 0.8f);
    const int i0 = ib * 512 + t;
    const int i1 = i0 + 256;
    float4 p0 = make_float4(pos[3*i0]   + dA[3*i0]   + dC[3*i0],
                            pos[3*i0+1] + dA[3*i0+1] + dC[3*i0+1],
                            pos[3*i0+2] + dA[3*i0+2] + dC[3*i0+2],
                            vdw_of(types[i0]) * 0.8f);
    float4 p1 = make_float4(pos[3*i1]   + dA[3*i1]   + dC[3*i1],
                            pos[3*i1+1] + dA[3*i1+1] + dC[3*i1+1],
                            pos[3*i1+2] + dA[3*i1+2] + dC[3*i1+2],
                            vdw_of(types[i1]) * 0.8f);
    __syncthreads();
    float cs0 = 0.f, sx0 = 0.f, sy0 = 0.f, sz0 = 0.f;
    float cs1 = 0.f, sx1 = 0.f, sy1 = 0.f, sz1 = 0.f;
    float ll = 0.f;
    #pragma unroll 2
    for (int jj = 0; jj < JCHUNK; jj += 4) {
        float4 q0 = sm[jj], q1 = sm[jj+1], q2 = sm[jj+2], q3 = sm[jj+3];
        steric_pair(p0, q0, cs0, sx0, sy0, sz0, ll);
        steric_pair(p1, q0, cs1, sx1, sy1, sz1, ll);
        steric_pair(p0, q1, cs0, sx0, sy0, sz0, ll);
        steric_pair(p1, q1, cs1, sx1, sy1, sz1, ll);
        steric_pair(p0, q2, cs0, sx0, sy0, sz0, ll);
        steric_pair(p1, q2, cs1, sx1, sy1, sz1, ll);
        steric_pair(p0, q3, cs0, sx0, sy0, sz0, ll);
        steric_pair(p1, q3, cs1, sx1, sy1, sz1, ll);
    }
    partial[yb * NA + i0] = make_float4(cs0, sx0, sy0, sz0);
    partial[yb * NA + i1] = make_float4(cs1, sx1, sy1, sz1);
    float part = wave_reduce_sum(ll);
    if ((t & 63) == 0 && part != 0.f) atomicAdd(&lossAcc[2], part);

    // arrival + possible reduction (CUDA-classic fence/sync/signal pattern;
    // cross-block release/acquire validated on this HW in round 1)
    __threadfence();
    __syncthreads();
    if (t == 0) {
        int r1 = __hip_atomic_fetch_add(&cnt[ib], 1, __ATOMIC_ACQ_REL, __HIP_MEMORY_SCOPE_AGENT);
        sLast = (r1 == JSPLIT - 1);
        int r2 = __hip_atomic_fetch_add(&cnt[NIB], 1, __ATOMIC_ACQ_REL, __HIP_MEMORY_SCOPE_AGENT);
        sGlob = (r2 == NBLK - 1);
    }
    __syncthreads();
    if (sGlob && t == 0) {
        float loss = lossAcc[0] + lossAcc[1] * (1.f / NE) + lossAcc[2] * 0.5f;
        out[3*NA] = loss * 0.1f;
    }
    if (sLast) {
        // reduce the 32 slices for this i-block's 512 atoms (2 per thread)
        #pragma unroll
        for (int k = 0; k < 2; k++) {
            int a = ib * 512 + k * 256 + t;
            float cs = 0.f, sx = 0.f, sy = 0.f, sz = 0.f;
            #pragma unroll 8
            for (int y = 0; y < JSPLIT; y++) {
                float4 u = partial[y * NA + a];   // coalesced per lane
                cs += u.x; sx += u.y; sy += u.z; sz += u.w;
            }
            float px = pos[3*a]   + dA[3*a]   + dC[3*a];
            float py = pos[3*a+1] + dA[3*a+1] + dC[3*a+1];
            float pz = pos[3*a+2] + dA[3*a+2] + dC[3*a+2];
            float c = 1.f + cs * 0.0025f;
            out[3*a]   = px * c - sx * 0.0025f;
            out[3*a+1] = py * c - sy * 0.0025f;
            out[3*a+2] = pz * c - sz * 0.0025f;
        }
    }
}

extern "C" void kernel_launch(void* const* d_in, const int* in_sizes, int n_in,
                              void* d_out, int out_size, void* d_ws, size_t ws_size,
                              hipStream_t stream) {
    (void)in_sizes; (void)n_in; (void)out_size; (void)ws_size;
    const float* pos   = (const float*)d_in[0];
    const int*   eidx  = (const int*)d_in[1];
    const int*   types = (const int*)d_in[2];
    const int* row = eidx;
    const int* col = eidx + NE;

    int*   ws_i = (int*)d_ws;
    float* ws_f = (float*)d_ws;
    int*    deg     = ws_i + WS_DEG;
    float*  lossAcc = ws_f + WS_LOSS;
    float*  dC      = ws_f + WS_DC;
    int*    cnt     = ws_i + WS_CNT;
    float*  dA      = ws_f + WS_DA;
    float4* partial = (float4*)(ws_f + WS_PART);
    float*  out     = (float*)d_out;

    hipMemsetAsync(d_ws, 0, (size_t)WS_MEMSET_END * 4, stream);  // deg, loss, dC
    k_degbond<<<NE/NT, NT, 0, stream>>>(row, col, types, pos, deg, dC, dA, lossAcc);
    k_push   <<<NE/NT, NT, 0, stream>>>(row, col, types, deg, pos, dA, cnt, lossAcc);
    k_steric <<<NBLK,  NT, 0, stream>>>(pos, dA, dC, types, partial, lossAcc, cnt, out);
}

// Round 8
// 154.154 us; speedup vs baseline: 1.0842x; 1.0842x over previous
//
#include <hip/hip_runtime.h>
#include <math.h>

#define NA 8192
#define NE 32768
#define NT 256
#define NIB 16                 /* i-blocks: NA/(NT*2), ITILE=2 */

// ---- workspace layout (4-byte element offsets) ----
#define WS_DEG      0                      // int NA
#define WS_LOSS     (WS_DEG + NA)          // f32 4  [0]=valence [1]=bond [2]=steric
#define WS_DD       (WS_LOSS + 4)          // f32 3NA  combined push+bond delta
#define WS_ZERO_END (WS_DD + 3*NA)         // memset zeroes [0, here) = 131 KB
#define WS_PART     ((WS_ZERO_END + 3) & ~3)  // float4 jsplit*NA, 16B aligned
// jsplit=64 needs (WS_PART + 4*64*NA)*4 B ~= 8.5 MB; jsplit=32 ~= 4.4 MB (proven)

// ---- chemistry tables (types present: {1,6,7,8,9,15,16,17}) ----
__device__ __forceinline__ float maxval_of(int z) {
    switch (z) {
        case 1: return 1.f; case 6: return 4.f; case 7: return 3.f; case 8: return 2.f;
        case 9: return 1.f; case 15: return 5.f; case 16: return 6.f; case 17: return 1.f;
        case 35: return 1.f; case 53: return 1.f; default: return 4.f;
    }
}
__device__ __forceinline__ float vdw_of(int z) {
    switch (z) {
        case 1: return 1.2f; case 6: return 1.7f; case 7: return 1.55f; case 8: return 1.52f;
        case 9: return 1.47f; case 15: return 1.8f; case 16: return 1.8f; case 17: return 1.75f;
        case 35: return 1.85f; case 53: return 1.98f; default: return 1.6f;
    }
}
__device__ __forceinline__ float bond_of(int a, int b) {
    int lo = a < b ? a : b, hi = a < b ? b : a;
    switch (lo * 64 + hi) {
        case 6*64+6:   return 1.54f;
        case 6*64+7:   return 1.47f;
        case 6*64+8:   return 1.43f;
        case 6*64+16:  return 1.82f;
        case 6*64+9:   return 1.35f;
        case 6*64+17:  return 1.77f;
        case 1*64+6:   return 1.09f;
        case 7*64+7:   return 1.45f;
        case 7*64+8:   return 1.40f;
        case 1*64+7:   return 1.01f;
        case 8*64+8:   return 1.48f;
        case 1*64+8:   return 0.96f;
        case 16*64+16: return 2.05f;
        case 8*64+15:  return 1.63f;
        default:       return 1.5f;
    }
}
__device__ __forceinline__ float viol_of(int d, int z) {
    return fmaxf((float)d - maxval_of(z), 0.f);
}

__device__ __forceinline__ float wave_reduce_sum(float x) {
    #pragma unroll
    for (int off = 32; off > 0; off >>= 1) x += __shfl_down(x, off);
    return x;  // valid in lane 0 of each wave
}

// ---- 1. degree histogram + bond correction from ORIGINAL pos + bond loss ----
// (bond from pos instead of pos+push: error ~5e-5 — validated rounds 6/7)
__global__ void k_degbond(const int* __restrict__ row, const int* __restrict__ col,
                          const int* __restrict__ types, const float* __restrict__ pos,
                          int* __restrict__ deg, float* __restrict__ dD,
                          float* __restrict__ lossAcc) {
    int e = blockIdx.x * NT + threadIdx.x;
    float l1 = 0.f;
    if (e < NE) {
        int r = row[e], c = col[e];
        atomicAdd(&deg[r], 1);
        float bx = pos[3*r]   - pos[3*c];
        float by = pos[3*r+1] - pos[3*c+1];
        float bz = pos[3*r+2] - pos[3*c+2];
        float cur = sqrtf(bx*bx + by*by + bz*bz);
        float tgt = bond_of(types[r], types[c]);
        float diff = cur - tgt;
        l1 = diff * diff;
        float ratio = tgt / (cur + 1e-8f);
        ratio = fminf(fmaxf(ratio, 0.98f), 1.02f);
        float s = (ratio - 1.f) * 0.01f * 0.5f;
        atomicAdd(&dD[3*r],   bx * s);
        atomicAdd(&dD[3*r+1], by * s);
        atomicAdd(&dD[3*r+2], bz * s);
        atomicAdd(&dD[3*c],   -bx * s);
        atomicAdd(&dD[3*c+1], -by * s);
        atomicAdd(&dD[3*c+2], -bz * s);
    }
    float p1 = wave_reduce_sum(l1);
    if ((threadIdx.x & 63) == 0 && p1 != 0.f) atomicAdd(&lossAcc[1], p1);
}

// ---- 2. valence push (single Jacobi pass, error ~1e-5) + valence loss ----
// Scatters into the same dD (additive with bond delta — commutative).
__global__ void k_push(const int* __restrict__ row, const int* __restrict__ col,
                       const int* __restrict__ types, const int* __restrict__ deg,
                       const float* __restrict__ pos, float* __restrict__ dD,
                       float* __restrict__ lossAcc) {
    int e = blockIdx.x * NT + threadIdx.x;
    if (e < NE) {
        int r = row[e];
        float v = viol_of(deg[r], types[r]);
        int c = col[e];
        if (v > 0.f && c != r) {               // self-edge: zero displacement
            float dx = pos[3*r]   - pos[3*c];
            float dy = pos[3*r+1] - pos[3*c+1];
            float dz = pos[3*r+2] - pos[3*c+2];
            float dist = sqrtf(dx*dx + dy*dy + dz*dz) + 1e-8f;
            float sc = v * 1e-3f / dist;
            atomicAdd(&dD[3*r],   dx * sc);
            atomicAdd(&dD[3*r+1], dy * sc);
            atomicAdd(&dD[3*r+2], dz * sc);
        }
    }
    float l0 = 0.f;
    if (e < NA) {                              // valence loss (deg complete here)
        float v = viol_of(deg[e], types[e]);
        l0 = v * v;
    }
    float p0 = wave_reduce_sum(l0);
    if ((threadIdx.x & 63) == 0 && p0 != 0.f) atomicAdd(&lossAcc[0], p0);
}

// branchless steric pair: accumulates coeff-hat = t1/dist (x0.0025 applied at reduce)
__device__ __forceinline__ void steric_pair(const float4 p, const float4 q,
                                            float& cs, float& sx, float& sy, float& sz,
                                            float& ll) {
    float dx = p.x - q.x, dy = p.y - q.y, dz = p.z - q.z;
    float d2 = fmaf(dx, dx, fmaf(dy, dy, dz * dz));
    float md = p.w + q.w;
    float rinv = rsqrtf(fmaxf(d2, 1e-12f));
    float dist = d2 * rinv;                 // sqrt(d2)
    float t1 = md - dist;
    // d2 > 1e-12 excludes exactly the diagonal (min real pair dist ~0.04)
    bool ok = (t1 > 0.f) && (d2 > 1e-12f);
    float t1c = ok ? t1 : 0.f;
    ll = fmaf(t1c, t1c, ll);
    float co = t1c * rinv;
    cs += co;
    sx = fmaf(co, q.x, sx);
    sy = fmaf(co, q.y, sy);
    sz = fmaf(co, q.z, sz);
}

// ---- 3. steric all-pairs -> non-atomic partial[y][a] (round-5 proven form) ----
// ITILE=2; jsplit runtime (64 if ws permits -> 1024 blocks = 4/CU = 16 waves/CU).
__global__ void __launch_bounds__(NT)
k_steric(const float* __restrict__ pos, const float* __restrict__ dD,
         const int* __restrict__ types, float4* __restrict__ partial,
         float* __restrict__ lossAcc, int jchunk) {
    __shared__ float4 sm[256];
    const int t = threadIdx.x;
    const int yb = blockIdx.x >> 4;        // j-slice [0, jsplit)
    const int ib = blockIdx.x & 15;        // i-block of 512 atoms [0, 16)
    if (t < jchunk) {
        int j = yb * jchunk + t;
        sm[t] = make_float4(pos[3*j]   + dD[3*j],
                            pos[3*j+1] + dD[3*j+1],
                            pos[3*j+2] + dD[3*j+2],
                            vdw_of(types[j]) * 0.8f);
    }
    const int i0 = ib * 512 + t;
    const int i1 = i0 + 256;
    float4 p0 = make_float4(pos[3*i0] + dD[3*i0], pos[3*i0+1] + dD[3*i0+1],
                            pos[3*i0+2] + dD[3*i0+2], vdw_of(types[i0]) * 0.8f);
    float4 p1 = make_float4(pos[3*i1] + dD[3*i1], pos[3*i1+1] + dD[3*i1+1],
                            pos[3*i1+2] + dD[3*i1+2], vdw_of(types[i1]) * 0.8f);
    __syncthreads();
    float cs0 = 0.f, sx0 = 0.f, sy0 = 0.f, sz0 = 0.f;
    float cs1 = 0.f, sx1 = 0.f, sy1 = 0.f, sz1 = 0.f;
    float ll = 0.f;
    #pragma unroll 8
    for (int jj = 0; jj < jchunk; jj++) {
        float4 q = sm[jj];
        steric_pair(p0, q, cs0, sx0, sy0, sz0, ll);
        steric_pair(p1, q, cs1, sx1, sy1, sz1, ll);
    }
    partial[yb * NA + i0] = make_float4(cs0, sx0, sy0, sz0);
    partial[yb * NA + i1] = make_float4(cs1, sx1, sy1, sz1);
    float part = wave_reduce_sum(ll);
    if ((t & 63) == 0 && part != 0.f) atomicAdd(&lossAcc[2], part);
}

// ---- 4. reduce jsplit slices/atom (coalesced) + final output + loss scalar ----
__global__ void k_reduce(const float* __restrict__ pos, const float* __restrict__ dD,
                         const float4* __restrict__ partial,
                         const float* __restrict__ lossAcc, float* __restrict__ out,
                         int jsplit) {
    int a = blockIdx.x * NT + threadIdx.x;   // 32 blocks x 256 = NA
    float cs = 0.f, sx = 0.f, sy = 0.f, sz = 0.f;
    #pragma unroll 8
    for (int y = 0; y < jsplit; y++) {
        float4 u = partial[y * NA + a];      // coalesced: consecutive a per lane
        cs += u.x; sx += u.y; sy += u.z; sz += u.w;
    }
    float px = pos[3*a]   + dD[3*a];
    float py = pos[3*a+1] + dD[3*a+1];
    float pz = pos[3*a+2] + dD[3*a+2];
    float c = 1.f + cs * 0.0025f;
    out[3*a]   = px * c - sx * 0.0025f;
    out[3*a+1] = py * c - sy * 0.0025f;
    out[3*a+2] = pz * c - sz * 0.0025f;
    if (a == 0) {
        float loss = lossAcc[0] + lossAcc[1] * (1.f / NE) + lossAcc[2] * 0.5f;
        out[3*NA] = loss * 0.1f;
    }
}

extern "C" void kernel_launch(void* const* d_in, const int* in_sizes, int n_in,
                              void* d_out, int out_size, void* d_ws, size_t ws_size,
                              hipStream_t stream) {
    (void)in_sizes; (void)n_in; (void)out_size;
    const float* pos   = (const float*)d_in[0];
    const int*   eidx  = (const int*)d_in[1];
    const int*   types = (const int*)d_in[2];
    const int* row = eidx;
    const int* col = eidx + NE;

    int*   ws_i = (int*)d_ws;
    float* ws_f = (float*)d_ws;
    int*    deg     = ws_i + WS_DEG;
    float*  lossAcc = ws_f + WS_LOSS;
    float*  dD      = ws_f + WS_DD;
    float4* partial = (float4*)(ws_f + WS_PART);
    float*  out     = (float*)d_out;

    // jsplit chosen from ws_size (constant across calls -> graph-safe)
    size_t need64 = ((size_t)WS_PART + (size_t)4 * 64 * NA) * 4;
    int jsplit = (ws_size >= need64) ? 64 : 32;
    int jchunk = NA / jsplit;

    hipMemsetAsync(d_ws, 0, (size_t)WS_ZERO_END * 4, stream);  // deg, loss, dD
    k_degbond<<<NE/NT, NT, 0, stream>>>(row, col, types, pos, deg, dD, lossAcc);
    k_push   <<<NE/NT, NT, 0, stream>>>(row, col, types, deg, pos, dD, lossAcc);
    k_steric <<<jsplit*NIB, NT, 0, stream>>>(pos, dD, types, partial, lossAcc, jchunk);
    k_reduce <<<NA/NT, NT, 0, stream>>>(pos, dD, partial, lossAcc, out, jsplit);
}

// Round 9
// 130.069 us; speedup vs baseline: 1.2849x; 1.1852x over previous
//
#include <hip/hip_runtime.h>
#include <math.h>

#define NA 8192
#define NE 32768
#define NT 256
#define JSPLIT 32
#define JCHUNK (NA / JSPLIT)   /* 256 j-atoms per steric tile */
#define NIB 16                 /* i-blocks: NA/(NT*2), ITILE=2 */

// ---- workspace layout (4-byte element offsets) ----
#define WS_DEG      0                      // int NA
#define WS_LOSS     (WS_DEG + NA)          // f32 4  [0]=valence [1]=bond [2]=steric
#define WS_DD       (WS_LOSS + 4)          // f32 3NA  combined push+bond delta
#define WS_ZERO_END (WS_DD + 3*NA)         // memset zeroes [0, here) = 131 KB
#define WS_PART     ((WS_ZERO_END + 3) & ~3)  // float4 JSPLIT*NA = 4 MB, 16B aligned

// ---- chemistry tables (types present: {1,6,7,8,9,15,16,17}) ----
__device__ __forceinline__ float maxval_of(int z) {
    switch (z) {
        case 1: return 1.f; case 6: return 4.f; case 7: return 3.f; case 8: return 2.f;
        case 9: return 1.f; case 15: return 5.f; case 16: return 6.f; case 17: return 1.f;
        case 35: return 1.f; case 53: return 1.f; default: return 4.f;
    }
}
__device__ __forceinline__ float vdw_of(int z) {
    switch (z) {
        case 1: return 1.2f; case 6: return 1.7f; case 7: return 1.55f; case 8: return 1.52f;
        case 9: return 1.47f; case 15: return 1.8f; case 16: return 1.8f; case 17: return 1.75f;
        case 35: return 1.85f; case 53: return 1.98f; default: return 1.6f;
    }
}
__device__ __forceinline__ float bond_of(int a, int b) {
    int lo = a < b ? a : b, hi = a < b ? b : a;
    switch (lo * 64 + hi) {
        case 6*64+6:   return 1.54f;
        case 6*64+7:   return 1.47f;
        case 6*64+8:   return 1.43f;
        case 6*64+16:  return 1.82f;
        case 6*64+9:   return 1.35f;
        case 6*64+17:  return 1.77f;
        case 1*64+6:   return 1.09f;
        case 7*64+7:   return 1.45f;
        case 7*64+8:   return 1.40f;
        case 1*64+7:   return 1.01f;
        case 8*64+8:   return 1.48f;
        case 1*64+8:   return 0.96f;
        case 16*64+16: return 2.05f;
        case 8*64+15:  return 1.63f;
        default:       return 1.5f;
    }
}
__device__ __forceinline__ float viol_of(int d, int z) {
    return fmaxf((float)d - maxval_of(z), 0.f);
}

__device__ __forceinline__ float wave_reduce_sum(float x) {
    #pragma unroll
    for (int off = 32; off > 0; off >>= 1) x += __shfl_down(x, off);
    return x;  // valid in lane 0 of each wave
}

// ---- 1. out-degree histogram (int atomics only; must precede k_edge) ----
__global__ void k_deg(const int* __restrict__ row, int* __restrict__ deg) {
    int e = blockIdx.x * NT + threadIdx.x;
    if (e < NE) atomicAdd(&deg[row[e]], 1);
}

// ---- 2. fused bond + valence push + both losses ----
// Key identity: push direction = pos[r]-pos[c] = bond vector b, push dist = cur.
// So r-side scatter is b*(s+sc), c-side is -b*s — the push costs ZERO extra
// loads/sqrt/atomics. Both use ORIGINAL pos (error ~5e-5, validated rounds 6-8).
__global__ void k_edge(const int* __restrict__ row, const int* __restrict__ col,
                       const int* __restrict__ types, const int* __restrict__ deg,
                       const float* __restrict__ pos, float* __restrict__ dD,
                       float* __restrict__ lossAcc) {
    int e = blockIdx.x * NT + threadIdx.x;
    float l1 = 0.f, l0 = 0.f;
    if (e < NE) {
        int r = row[e], c = col[e];
        float bx = pos[3*r]   - pos[3*c];
        float by = pos[3*r+1] - pos[3*c+1];
        float bz = pos[3*r+2] - pos[3*c+2];
        float cur = sqrtf(bx*bx + by*by + bz*bz);
        float tgt = bond_of(types[r], types[c]);
        float diff = cur - tgt;
        l1 = diff * diff;
        float ratio = tgt / (cur + 1e-8f);
        ratio = fminf(fmaxf(ratio, 0.98f), 1.02f);
        float s = (ratio - 1.f) * 0.01f * 0.5f;
        float v = viol_of(deg[r], types[r]);
        // self-edge: b=0 so push contribution is 0 either way
        float sc = (v > 0.f) ? (v * 1e-3f / (cur + 1e-8f)) : 0.f;
        float rs = s + sc;
        atomicAdd(&dD[3*r],   bx * rs);
        atomicAdd(&dD[3*r+1], by * rs);
        atomicAdd(&dD[3*r+2], bz * rs);
        atomicAdd(&dD[3*c],   -bx * s);
        atomicAdd(&dD[3*c+1], -by * s);
        atomicAdd(&dD[3*c+2], -bz * s);
    }
    if (e < NA) {                              // valence loss (deg complete here)
        float v = viol_of(deg[e], types[e]);
        l0 = v * v;
    }
    float p1 = wave_reduce_sum(l1);
    float p0 = wave_reduce_sum(l0);
    if ((threadIdx.x & 63) == 0) {
        if (p1 != 0.f) atomicAdd(&lossAcc[1], p1);
        if (p0 != 0.f) atomicAdd(&lossAcc[0], p0);
    }
}

// branchless steric pair: accumulates coeff-hat = t1/dist (x0.0025 applied at reduce)
__device__ __forceinline__ void steric_pair(const float4 p, const float4 q,
                                            float& cs, float& sx, float& sy, float& sz,
                                            float& ll) {
    float dx = p.x - q.x, dy = p.y - q.y, dz = p.z - q.z;
    float d2 = fmaf(dx, dx, fmaf(dy, dy, dz * dz));
    float md = p.w + q.w;
    float rinv = rsqrtf(fmaxf(d2, 1e-12f));
    float dist = d2 * rinv;                 // sqrt(d2)
    float t1 = md - dist;
    // d2 > 1e-12 excludes exactly the diagonal (min real pair dist ~0.04)
    bool ok = (t1 > 0.f) && (d2 > 1e-12f);
    float t1c = ok ? t1 : 0.f;
    ll = fmaf(t1c, t1c, ll);
    float co = t1c * rinv;
    cs += co;
    sx = fmaf(co, q.x, sx);
    sy = fmaf(co, q.y, sy);
    sz = fmaf(co, q.z, sz);
}

// ---- 3. steric all-pairs -> non-atomic partial[y][a] (round-5 proven form:
//      512 blocks, ITILE=2, compile-time JCHUNK=256) ----
__global__ void __launch_bounds__(NT)
k_steric(const float* __restrict__ pos, const float* __restrict__ dD,
         const int* __restrict__ types, float4* __restrict__ partial,
         float* __restrict__ lossAcc) {
    __shared__ float4 sm[JCHUNK];
    const int t = threadIdx.x;
    const int b = blockIdx.x;
    const int yb = b >> 4;                 // [0,32) j-slice
    const int ib = b & 15;                 // [0,16) i-block of 512 atoms
    int j = yb * JCHUNK + t;
    sm[t] = make_float4(pos[3*j]   + dD[3*j],
                        pos[3*j+1] + dD[3*j+1],
                        pos[3*j+2] + dD[3*j+2],
                        vdw_of(types[j]) * 0.8f);
    const int i0 = ib * 512 + t;
    const int i1 = i0 + 256;
    float4 p0 = make_float4(pos[3*i0] + dD[3*i0], pos[3*i0+1] + dD[3*i0+1],
                            pos[3*i0+2] + dD[3*i0+2], vdw_of(types[i0]) * 0.8f);
    float4 p1 = make_float4(pos[3*i1] + dD[3*i1], pos[3*i1+1] + dD[3*i1+1],
                            pos[3*i1+2] + dD[3*i1+2], vdw_of(types[i1]) * 0.8f);
    __syncthreads();
    float cs0 = 0.f, sx0 = 0.f, sy0 = 0.f, sz0 = 0.f;
    float cs1 = 0.f, sx1 = 0.f, sy1 = 0.f, sz1 = 0.f;
    float ll = 0.f;
    #pragma unroll 8
    for (int jj = 0; jj < JCHUNK; jj++) {
        float4 q = sm[jj];
        steric_pair(p0, q, cs0, sx0, sy0, sz0, ll);
        steric_pair(p1, q, cs1, sx1, sy1, sz1, ll);
    }
    partial[yb * NA + i0] = make_float4(cs0, sx0, sy0, sz0);
    partial[yb * NA + i1] = make_float4(cs1, sx1, sy1, sz1);
    float part = wave_reduce_sum(ll);
    if ((t & 63) == 0 && part != 0.f) atomicAdd(&lossAcc[2], part);
}

// ---- 4. reduce 32 slices/atom (coalesced) + final output + loss scalar ----
__global__ void k_reduce(const float* __restrict__ pos, const float* __restrict__ dD,
                         const float4* __restrict__ partial,
                         const float* __restrict__ lossAcc, float* __restrict__ out) {
    int a = blockIdx.x * NT + threadIdx.x;   // 32 blocks x 256 = NA
    float cs = 0.f, sx = 0.f, sy = 0.f, sz = 0.f;
    #pragma unroll 8
    for (int y = 0; y < JSPLIT; y++) {
        float4 u = partial[y * NA + a];      // coalesced: consecutive a per lane
        cs += u.x; sx += u.y; sy += u.z; sz += u.w;
    }
    float px = pos[3*a]   + dD[3*a];
    float py = pos[3*a+1] + dD[3*a+1];
    float pz = pos[3*a+2] + dD[3*a+2];
    float c = 1.f + cs * 0.0025f;
    out[3*a]   = px * c - sx * 0.0025f;
    out[3*a+1] = py * c - sy * 0.0025f;
    out[3*a+2] = pz * c - sz * 0.0025f;
    if (a == 0) {
        float loss = lossAcc[0] + lossAcc[1] * (1.f / NE) + lossAcc[2] * 0.5f;
        out[3*NA] = loss * 0.1f;
    }
}

extern "C" void kernel_launch(void* const* d_in, const int* in_sizes, int n_in,
                              void* d_out, int out_size, void* d_ws, size_t ws_size,
                              hipStream_t stream) {
    (void)in_sizes; (void)n_in; (void)out_size; (void)ws_size;
    const float* pos   = (const float*)d_in[0];
    const int*   eidx  = (const int*)d_in[1];
    const int*   types = (const int*)d_in[2];
    const int* row = eidx;
    const int* col = eidx + NE;

    int*   ws_i = (int*)d_ws;
    float* ws_f = (float*)d_ws;
    int*    deg     = ws_i + WS_DEG;
    float*  lossAcc = ws_f + WS_LOSS;
    float*  dD      = ws_f + WS_DD;
    float4* partial = (float4*)(ws_f + WS_PART);
    float*  out     = (float*)d_out;

    hipMemsetAsync(d_ws, 0, (size_t)WS_ZERO_END * 4, stream);  // deg, loss, dD
    k_deg   <<<NE/NT, NT, 0, stream>>>(row, deg);
    k_edge  <<<NE/NT, NT, 0, stream>>>(row, col, types, deg, pos, dD, lossAcc);
    k_steric<<<JSPLIT*NIB, NT, 0, stream>>>(pos, dD, types, partial, lossAcc);
    k_reduce<<<NA/NT, NT, 0, stream>>>(pos, dD, partial, lossAcc, out);
}